// Round 3
// baseline (185.217 us; speedup 1.0000x reference)
//
#include <hip/hip_runtime.h>

constexpr int NB  = 16384;  // batch
constexpr int ND  = 3072;   // D
constexpr int NR  = 256;    // R
constexpr int NE  = 8;      // experts
constexpr int NO1 = 16;     // L2+1 outputs of l1
constexpr int NL2D = 30;    // 2*L2
constexpr int NL3 = 32;     // L3

// ---- workspace layout (bytes) ----
constexpr size_t WS_CURSORS = 32;     // int[8]
constexpr size_t WS_OFFPAD  = 128;    // int[9]
constexpr size_t WS_IDX     = 256;                    // int[NB]
constexpr size_t WS_BUCKET  = WS_IDX + (size_t)NB*4;  // int[NB+256]
constexpr size_t WS_MB      = WS_BUCKET + (size_t)(NB+256)*4; // float[128]
constexpr size_t WS_MW      = WS_MB + 512;            // float[128*3072]
constexpr size_t WS_BLK_CNT  = WS_MW + (size_t)128*3072*4;   // int[256*8]
constexpr size_t WS_BLK_SUMP = WS_BLK_CNT + 8192;            // float[256*8]
constexpr size_t WS_BLK_Z    = WS_BLK_SUMP + 8192;           // float[256]
constexpr size_t WS_BLK_ENT  = WS_BLK_Z + 1024;              // float[256]
constexpr size_t WS_BLK_TOP  = WS_BLK_ENT + 1024;            // float[256]

__device__ __forceinline__ float clamp01(float v) { return fminf(fmaxf(v, 0.0f), 1.0f); }

// ---------------- Router v2: 64 rows/block, 4 threads/row ----------------
__global__ __launch_bounds__(256) void router2_kernel(
    const float* __restrict__ rin, const float* __restrict__ rw,
    const float* __restrict__ rb, int* __restrict__ idx,
    int* __restrict__ blk_cnt, float* __restrict__ blk_sump,
    float* __restrict__ blk_z, float* __restrict__ blk_ent, float* __restrict__ blk_top)
{
    __shared__ float w_s[NE][NR];          // 8 KB
    __shared__ float red_f[4][11];
    __shared__ int   red_c[4][8];

    const int t = threadIdx.x;
    {
        const float4* src = (const float4*)rw;
        float4* dst = (float4*)&w_s[0][0];
        dst[t]       = src[t];
        dst[t + 256] = src[t + 256];
    }
    __syncthreads();

    const int q  = t & 3;          // quarter of the row (64 elems each)
    const int rr = t >> 2;         // row within block, 0..63
    const int b  = blockIdx.x * 64 + rr;
    const float* rp = rin + (size_t)b * NR + q * 64;

    float acc[NE];
#pragma unroll
    for (int e = 0; e < NE; ++e) acc[e] = 0.0f;

#pragma unroll
    for (int c = 0; c < 16; ++c) {
        const float4 xv = *(const float4*)(rp + c * 4);
#pragma unroll
        for (int e = 0; e < NE; ++e) {
            const float4 wv = *(const float4*)(&w_s[e][q * 64 + c * 4]);
            acc[e] = fmaf(xv.x, wv.x, acc[e]);
            acc[e] = fmaf(xv.y, wv.y, acc[e]);
            acc[e] = fmaf(xv.z, wv.z, acc[e]);
            acc[e] = fmaf(xv.w, wv.w, acc[e]);
        }
    }
    float lg[NE];
#pragma unroll
    for (int e = 0; e < NE; ++e) {
        float v = acc[e];
        v += __shfl_xor(v, 1);
        v += __shfl_xor(v, 2);
        lg[e] = v + rb[e];
    }

    float m = lg[0]; int am = 0;
#pragma unroll
    for (int e = 1; e < NE; ++e) { if (lg[e] > m) { m = lg[e]; am = e; } }
    float p[NE]; float ssum = 0.0f;
#pragma unroll
    for (int e = 0; e < NE; ++e) { p[e] = __expf(lg[e] - m); ssum += p[e]; }
    const float inv = 1.0f / ssum;
    const float lse = m + __logf(ssum);

    const bool active = (q == 0);
    float sv[11];
    float ent = 0.0f, top = 0.0f;
#pragma unroll
    for (int e = 0; e < NE; ++e) {
        const float pj = p[e] * inv;
        sv[e] = pj;
        ent -= pj * __logf(fmaxf(pj, 1e-9f));
        top = fmaxf(top, pj);
    }
    sv[8] = lse * lse;
    sv[9] = ent;
    sv[10] = top;
    if (!active) {
#pragma unroll
        for (int i = 0; i < 11; ++i) sv[i] = 0.0f;
    }
    if (active) idx[b] = am;

#pragma unroll
    for (int i = 0; i < 11; ++i) {
        float v = sv[i];
        v += __shfl_xor(v, 4);
        v += __shfl_xor(v, 8);
        v += __shfl_xor(v, 16);
        v += __shfl_xor(v, 32);
        sv[i] = v;
    }
    int cnt[NE];
#pragma unroll
    for (int j = 0; j < NE; ++j) {
        unsigned long long mk = __ballot(active && (am == j));
        cnt[j] = __popcll(mk);
    }

    const int wave = t >> 6;
    if ((t & 63) == 0) {
#pragma unroll
        for (int i = 0; i < 11; ++i) red_f[wave][i] = sv[i];
#pragma unroll
        for (int j = 0; j < NE; ++j) red_c[wave][j] = cnt[j];
    }
    __syncthreads();

    const int bid = blockIdx.x;
    if (t < 8) {
        blk_sump[bid * 8 + t] = red_f[0][t] + red_f[1][t] + red_f[2][t] + red_f[3][t];
        blk_cnt [bid * 8 + t] = red_c[0][t] + red_c[1][t] + red_c[2][t] + red_c[3][t];
    } else if (t == 8) {
        blk_z[bid]   = red_f[0][8] + red_f[1][8] + red_f[2][8] + red_f[3][8];
    } else if (t == 9) {
        blk_ent[bid] = red_f[0][9] + red_f[1][9] + red_f[2][9] + red_f[3][9];
    } else if (t == 10) {
        blk_top[bid] = red_f[0][10] + red_f[1][10] + red_f[2][10] + red_f[3][10];
    }
}

// ---------------- Merge l1 weights: merged = l1_w + tile(l1f_w) ----------------
__global__ __launch_bounds__(256) void merge_kernel(
    const float* __restrict__ l1w, const float* __restrict__ l1b,
    const float* __restrict__ l1fw, const float* __restrict__ l1fb,
    float* __restrict__ mw, float* __restrict__ mb)
{
    const int i = blockIdx.x * 256 + threadIdx.x;
    const int total = NE * NO1 * ND;   // 128*3072
    if (i < total) {
        mw[i] = l1w[i] + l1fw[i % (NO1 * ND)];
    }
    if (i < NE * NO1) {
        mb[i] = l1b[i] + l1fb[i & (NO1 - 1)];
    }
}

// ---------------- Finalize v2: reduce 256 per-block partials ----------------
__global__ __launch_bounds__(256) void finalize2_kernel(
    const int* __restrict__ blk_cnt, const float* __restrict__ blk_sump,
    const float* __restrict__ blk_z, const float* __restrict__ blk_ent,
    const float* __restrict__ blk_top, int* __restrict__ offpad,
    float* __restrict__ out)
{
    __shared__ float ps_s[32][8];
    __shared__ int   pc_s[32][8];
    __shared__ float zet_s[3][4];
    __shared__ float tot_f[8];
    __shared__ int   tot_c[8];

    const int t = threadIdx.x;
    {
        const int e = t & 7, g = t >> 3;
        float ps = 0.0f; int pc = 0;
#pragma unroll
        for (int k = 0; k < 8; ++k) {
            const int bb = g * 8 + k;
            ps += blk_sump[bb * 8 + e];
            pc += blk_cnt [bb * 8 + e];
        }
        ps_s[g][e] = ps;
        pc_s[g][e] = pc;
    }
    {
        float z = blk_z[t], en = blk_ent[t], tp = blk_top[t];
#pragma unroll
        for (int o = 1; o < 64; o <<= 1) {
            z  += __shfl_xor(z, o);
            en += __shfl_xor(en, o);
            tp += __shfl_xor(tp, o);
        }
        const int wave = t >> 6;
        if ((t & 63) == 0) { zet_s[0][wave] = z; zet_s[1][wave] = en; zet_s[2][wave] = tp; }
    }
    __syncthreads();

    if (t < 8) {
        float s = 0.0f; int c = 0;
        for (int g = 0; g < 32; ++g) { s += ps_s[g][t]; c += pc_s[g][t]; }
        tot_f[t] = s; tot_c[t] = c;
    }
    __syncthreads();

    if (t == 0) {
        int run = 0;
#pragma unroll
        for (int e = 0; e < NE; ++e) {
            offpad[e] = run;
            run += (tot_c[e] + 31) & ~31;
        }
        offpad[NE] = run;

        const float invB = 1.0f / (float)NB;
        float aux = 0.0f;
        float frac[NE], avg[NE];
#pragma unroll
        for (int e = 0; e < NE; ++e) {
            frac[e] = (float)tot_c[e] * invB;
            avg[e]  = tot_f[e] * invB;
            aux += frac[e] * avg[e];
        }
        aux *= (float)NE;
        const float z   = (zet_s[0][0] + zet_s[0][1] + zet_s[0][2] + zet_s[0][3]) * invB;
        const float ent = (zet_s[1][0] + zet_s[1][1] + zet_s[1][2] + zet_s[1][3]) * invB;
        const float top = (zet_s[2][0] + zet_s[2][1] + zet_s[2][2] + zet_s[2][3]) * invB;
        const float rl  = 0.01f * aux + 0.001f * z;

        float* o = out + NB;
        o[0] = rl;
        o[1] = aux;
        o[2] = z;
#pragma unroll
        for (int e = 0; e < NE; ++e) o[3 + e]  = frac[e];
#pragma unroll
        for (int e = 0; e < NE; ++e) o[11 + e] = avg[e];
        o[19] = ent / __logf(8.0f);
        o[20] = top;
    }
}

// ---------------- Scatter rows into expert buckets (wave-aggregated atomics) ----------------
__global__ __launch_bounds__(256) void scatter_kernel(
    const int* __restrict__ idx, const int* __restrict__ offpad,
    int* __restrict__ cursors, int* __restrict__ bucket)
{
    const int b = blockIdx.x * 256 + threadIdx.x;
    const int e = idx[b];
    const int lane = threadIdx.x & 63;
#pragma unroll
    for (int ee = 0; ee < NE; ++ee) {
        unsigned long long mask = __ballot(e == ee);
        if (e == ee) {
            int leader = __ffsll((unsigned long long)mask) - 1;
            int cnt = __popcll(mask);
            int base = 0;
            if (lane == leader) base = atomicAdd(&cursors[ee], cnt);
            base = __shfl(base, leader);
            int pos = base + __popcll(mask & ((1ull << lane) - 1ull));
            bucket[offpad[ee] + pos] = b;
        }
    }
}

// ---------------- Main v3: 8 rows/block, 1 row per 8-lane group ----------------
__global__ __launch_bounds__(256, 6) void moe_main_kernel(
    const float* __restrict__ x, const float* __restrict__ mw,
    const float* __restrict__ mb, const float* __restrict__ l2w,
    const float* __restrict__ l2b, const float* __restrict__ ow,
    const float* __restrict__ ob, const int* __restrict__ bucket,
    const int* __restrict__ offpad, float* __restrict__ out)
{
    __shared__ int   rows_s[8];
    __shared__ int   expert_s;
    __shared__ float part_s[4][8][16];   // per-wave partial l1c
    __shared__ float l1x_s[8][30];
    __shared__ float l1c15_s[8];

    const int t = threadIdx.x;
    const int slot0 = blockIdx.x * 8;
    if (t < 8) rows_s[t] = bucket[slot0 + t];
    if (t == 0) {
        int e = 0;
#pragma unroll
        for (int j = 1; j < NE; ++j) if (slot0 >= offpad[j]) e = j;
        expert_s = e;
    }
    __syncthreads();

    const int e = expert_s;
    const int wave = t >> 6;      // K-quarter
    const int lane = t & 63;
    const int rgrp = lane >> 3;   // 8 row-groups, 1 row each
    const int s    = lane & 7;    // 8 k-slices (float4 interleave)

    const int row = rows_s[rgrp];
    const float* xp = x + (size_t)(row < 0 ? 0 : row) * ND;
    const float* wb = mw + (size_t)e * NO1 * ND;

    float acc[16];
#pragma unroll
    for (int o = 0; o < 16; ++o) acc[o] = 0.0f;

    const int k0 = wave * 768 + s * 4;
    float4 xr = *(const float4*)(xp + k0);
    for (int step = 0; step < 24; ++step) {
        const int kb = k0 + step * 32;
        // prefetch next step's x (safe pointer for the last step)
        const float* nxt = (step < 23) ? (xp + kb + 32) : (xp + k0);
        const float4 xn = *(const float4*)nxt;
        const float* wk = wb + kb;
#pragma unroll
        for (int o = 0; o < 16; ++o) {
            const float4 w = *(const float4*)(wk + (size_t)o * ND);
            float a = acc[o];
            a = fmaf(xr.x, w.x, a);
            a = fmaf(xr.y, w.y, a);
            a = fmaf(xr.z, w.z, a);
            a = fmaf(xr.w, w.w, a);
            acc[o] = a;
        }
        xr = xn;
    }

    // reduce over s (8 k-slices)
#pragma unroll
    for (int o = 0; o < 16; ++o) {
        float a = acc[o];
        a += __shfl_xor(a, 1);
        a += __shfl_xor(a, 2);
        a += __shfl_xor(a, 4);
        acc[o] = a;
    }
    if (s == 0) {
#pragma unroll
        for (int o = 0; o < 16; ++o)
            part_s[wave][rgrp][o] = acc[o];
    }
    __syncthreads();

    // ---- tail: l1 activation, l2, l3 ----
    const int r = t >> 5;   // row 0..7
    const int q = t & 31;   // 32 threads per row
    const int rowb = rows_s[r];

    if (q < 16) {
        const int o = q;
        float v = part_s[0][r][o] + part_s[1][r][o] + part_s[2][r][o]
                + part_s[3][r][o] + mb[e * NO1 + o];
        if (o < 15) {
            l1x_s[r][o]      = clamp01(v * v * (255.0f / 256.0f));
            l1x_s[r][o + 15] = clamp01(v);
        } else {
            l1c15_s[r] = v;
        }
    }
    __syncthreads();

    float a2 = l2b[e * NL3 + q];
    const float* w2r = l2w + (size_t)e * NL3 * NL2D + q * NL2D;
#pragma unroll
    for (int i = 0; i < NL2D; ++i) a2 = fmaf(l1x_s[r][i], w2r[i], a2);
    a2 = clamp01(a2);
    float pacc = a2 * ow[e * NL3 + q];
    pacc += __shfl_xor(pacc, 1);
    pacc += __shfl_xor(pacc, 2);
    pacc += __shfl_xor(pacc, 4);
    pacc += __shfl_xor(pacc, 8);
    pacc += __shfl_xor(pacc, 16);

    if (q == 0 && rowb >= 0) {
        out[rowb] = pacc + ob[e] + l1c15_s[r];
    }
}

extern "C" void kernel_launch(void* const* d_in, const int* in_sizes, int n_in,
                              void* d_out, int out_size, void* d_ws, size_t ws_size,
                              hipStream_t stream)
{
    const float* x    = (const float*)d_in[0];
    const float* rin  = (const float*)d_in[1];
    const float* rw   = (const float*)d_in[2];
    const float* rb   = (const float*)d_in[3];
    const float* l1w  = (const float*)d_in[4];
    const float* l1b  = (const float*)d_in[5];
    const float* l1fw = (const float*)d_in[6];
    const float* l1fb = (const float*)d_in[7];
    const float* l2w  = (const float*)d_in[8];
    const float* l2b  = (const float*)d_in[9];
    const float* ow   = (const float*)d_in[10];
    const float* ob   = (const float*)d_in[11];
    float* out = (float*)d_out;

    char* ws = (char*)d_ws;
    int*   cursors = (int*)(ws + WS_CURSORS);
    int*   offpad  = (int*)(ws + WS_OFFPAD);
    int*   idx     = (int*)(ws + WS_IDX);
    int*   bucket  = (int*)(ws + WS_BUCKET);
    float* mb      = (float*)(ws + WS_MB);
    float* mw      = (float*)(ws + WS_MW);
    int*   blk_cnt  = (int*)(ws + WS_BLK_CNT);
    float* blk_sump = (float*)(ws + WS_BLK_SUMP);
    float* blk_z    = (float*)(ws + WS_BLK_Z);
    float* blk_ent  = (float*)(ws + WS_BLK_ENT);
    float* blk_top  = (float*)(ws + WS_BLK_TOP);

    hipMemsetAsync(ws, 0, 256, stream);
    hipMemsetAsync(ws + WS_BUCKET, 0xFF, (size_t)(NB + 256) * 4, stream);

    router2_kernel<<<NB / 64, 256, 0, stream>>>(rin, rw, rb, idx, blk_cnt, blk_sump,
                                                blk_z, blk_ent, blk_top);
    merge_kernel<<<(NE * NO1 * ND + 255) / 256, 256, 0, stream>>>(l1w, l1b, l1fw, l1fb, mw, mb);
    finalize2_kernel<<<1, 256, 0, stream>>>(blk_cnt, blk_sump, blk_z, blk_ent, blk_top,
                                            offpad, out);
    scatter_kernel<<<NB / 256, 256, 0, stream>>>(idx, offpad, cursors, bucket);
    moe_main_kernel<<<(NB + 256) / 8, 256, 0, stream>>>(x, mw, mb, l2w, l2b, ow, ob,
                                                        bucket, offpad, out);
}

// Round 4
// 181.814 us; speedup vs baseline: 1.0187x; 1.0187x over previous
//
#include <hip/hip_runtime.h>

constexpr int NB  = 16384;  // batch
constexpr int ND  = 3072;   // D
constexpr int NR  = 256;    // R
constexpr int NE  = 8;      // experts
constexpr int NO1 = 16;     // L2+1 outputs of l1
constexpr int NL2D = 30;    // 2*L2
constexpr int NL3 = 32;     // L3

// ---- workspace layout (bytes) ----
constexpr size_t WS_CURSORS = 32;     // int[8]
constexpr size_t WS_OFFPAD  = 128;    // int[9]
constexpr size_t WS_IDX     = 256;                    // int[NB]
constexpr size_t WS_BUCKET  = WS_IDX + (size_t)NB*4;  // int[NB+256]
constexpr size_t WS_MB      = WS_BUCKET + (size_t)(NB+256)*4; // float[128]
constexpr size_t WS_MW      = WS_MB + 512;            // float[128*3072]
constexpr size_t WS_BLK_CNT  = WS_MW + (size_t)128*3072*4;   // int[256*8]
constexpr size_t WS_BLK_SUMP = WS_BLK_CNT + 8192;            // float[256*8]
constexpr size_t WS_BLK_Z    = WS_BLK_SUMP + 8192;           // float[256]
constexpr size_t WS_BLK_ENT  = WS_BLK_Z + 1024;              // float[256]
constexpr size_t WS_BLK_TOP  = WS_BLK_ENT + 1024;            // float[256]

__device__ __forceinline__ float clamp01(float v) { return fminf(fmaxf(v, 0.0f), 1.0f); }

// ---------------- Router v2: 64 rows/block, 4 threads/row ----------------
__global__ __launch_bounds__(256) void router2_kernel(
    const float* __restrict__ rin, const float* __restrict__ rw,
    const float* __restrict__ rb, int* __restrict__ idx,
    int* __restrict__ blk_cnt, float* __restrict__ blk_sump,
    float* __restrict__ blk_z, float* __restrict__ blk_ent, float* __restrict__ blk_top)
{
    __shared__ float w_s[NE][NR];          // 8 KB
    __shared__ float red_f[4][11];
    __shared__ int   red_c[4][8];

    const int t = threadIdx.x;
    {
        const float4* src = (const float4*)rw;
        float4* dst = (float4*)&w_s[0][0];
        dst[t]       = src[t];
        dst[t + 256] = src[t + 256];
    }
    __syncthreads();

    const int q  = t & 3;          // quarter of the row (64 elems each)
    const int rr = t >> 2;         // row within block, 0..63
    const int b  = blockIdx.x * 64 + rr;
    const float* rp = rin + (size_t)b * NR + q * 64;

    float acc[NE];
#pragma unroll
    for (int e = 0; e < NE; ++e) acc[e] = 0.0f;

#pragma unroll
    for (int c = 0; c < 16; ++c) {
        const float4 xv = *(const float4*)(rp + c * 4);
#pragma unroll
        for (int e = 0; e < NE; ++e) {
            const float4 wv = *(const float4*)(&w_s[e][q * 64 + c * 4]);
            acc[e] = fmaf(xv.x, wv.x, acc[e]);
            acc[e] = fmaf(xv.y, wv.y, acc[e]);
            acc[e] = fmaf(xv.z, wv.z, acc[e]);
            acc[e] = fmaf(xv.w, wv.w, acc[e]);
        }
    }
    float lg[NE];
#pragma unroll
    for (int e = 0; e < NE; ++e) {
        float v = acc[e];
        v += __shfl_xor(v, 1);
        v += __shfl_xor(v, 2);
        lg[e] = v + rb[e];
    }

    float m = lg[0]; int am = 0;
#pragma unroll
    for (int e = 1; e < NE; ++e) { if (lg[e] > m) { m = lg[e]; am = e; } }
    float p[NE]; float ssum = 0.0f;
#pragma unroll
    for (int e = 0; e < NE; ++e) { p[e] = __expf(lg[e] - m); ssum += p[e]; }
    const float inv = 1.0f / ssum;
    const float lse = m + __logf(ssum);

    const bool active = (q == 0);
    float sv[11];
    float ent = 0.0f, top = 0.0f;
#pragma unroll
    for (int e = 0; e < NE; ++e) {
        const float pj = p[e] * inv;
        sv[e] = pj;
        ent -= pj * __logf(fmaxf(pj, 1e-9f));
        top = fmaxf(top, pj);
    }
    sv[8] = lse * lse;
    sv[9] = ent;
    sv[10] = top;
    if (!active) {
#pragma unroll
        for (int i = 0; i < 11; ++i) sv[i] = 0.0f;
    }
    if (active) idx[b] = am;

#pragma unroll
    for (int i = 0; i < 11; ++i) {
        float v = sv[i];
        v += __shfl_xor(v, 4);
        v += __shfl_xor(v, 8);
        v += __shfl_xor(v, 16);
        v += __shfl_xor(v, 32);
        sv[i] = v;
    }
    int cnt[NE];
#pragma unroll
    for (int j = 0; j < NE; ++j) {
        unsigned long long mk = __ballot(active && (am == j));
        cnt[j] = __popcll(mk);
    }

    const int wave = t >> 6;
    if ((t & 63) == 0) {
#pragma unroll
        for (int i = 0; i < 11; ++i) red_f[wave][i] = sv[i];
#pragma unroll
        for (int j = 0; j < NE; ++j) red_c[wave][j] = cnt[j];
    }
    __syncthreads();

    const int bid = blockIdx.x;
    if (t < 8) {
        blk_sump[bid * 8 + t] = red_f[0][t] + red_f[1][t] + red_f[2][t] + red_f[3][t];
        blk_cnt [bid * 8 + t] = red_c[0][t] + red_c[1][t] + red_c[2][t] + red_c[3][t];
    } else if (t == 8) {
        blk_z[bid]   = red_f[0][8] + red_f[1][8] + red_f[2][8] + red_f[3][8];
    } else if (t == 9) {
        blk_ent[bid] = red_f[0][9] + red_f[1][9] + red_f[2][9] + red_f[3][9];
    } else if (t == 10) {
        blk_top[bid] = red_f[0][10] + red_f[1][10] + red_f[2][10] + red_f[3][10];
    }
}

// ---------------- Merge l1 weights: merged = l1_w + tile(l1f_w) ----------------
__global__ __launch_bounds__(256) void merge_kernel(
    const float* __restrict__ l1w, const float* __restrict__ l1b,
    const float* __restrict__ l1fw, const float* __restrict__ l1fb,
    float* __restrict__ mw, float* __restrict__ mb)
{
    const int i = blockIdx.x * 256 + threadIdx.x;
    const int total = NE * NO1 * ND;   // 128*3072
    if (i < total) {
        mw[i] = l1w[i] + l1fw[i % (NO1 * ND)];
    }
    if (i < NE * NO1) {
        mb[i] = l1b[i] + l1fb[i & (NO1 - 1)];
    }
}

// ---------------- Finalize v2: reduce 256 per-block partials ----------------
__global__ __launch_bounds__(256) void finalize2_kernel(
    const int* __restrict__ blk_cnt, const float* __restrict__ blk_sump,
    const float* __restrict__ blk_z, const float* __restrict__ blk_ent,
    const float* __restrict__ blk_top, int* __restrict__ offpad,
    float* __restrict__ out)
{
    __shared__ float ps_s[32][8];
    __shared__ int   pc_s[32][8];
    __shared__ float zet_s[3][4];
    __shared__ float tot_f[8];
    __shared__ int   tot_c[8];

    const int t = threadIdx.x;
    {
        const int e = t & 7, g = t >> 3;
        float ps = 0.0f; int pc = 0;
#pragma unroll
        for (int k = 0; k < 8; ++k) {
            const int bb = g * 8 + k;
            ps += blk_sump[bb * 8 + e];
            pc += blk_cnt [bb * 8 + e];
        }
        ps_s[g][e] = ps;
        pc_s[g][e] = pc;
    }
    {
        float z = blk_z[t], en = blk_ent[t], tp = blk_top[t];
#pragma unroll
        for (int o = 1; o < 64; o <<= 1) {
            z  += __shfl_xor(z, o);
            en += __shfl_xor(en, o);
            tp += __shfl_xor(tp, o);
        }
        const int wave = t >> 6;
        if ((t & 63) == 0) { zet_s[0][wave] = z; zet_s[1][wave] = en; zet_s[2][wave] = tp; }
    }
    __syncthreads();

    if (t < 8) {
        float s = 0.0f; int c = 0;
        for (int g = 0; g < 32; ++g) { s += ps_s[g][t]; c += pc_s[g][t]; }
        tot_f[t] = s; tot_c[t] = c;
    }
    __syncthreads();

    if (t == 0) {
        int run = 0;
#pragma unroll
        for (int e = 0; e < NE; ++e) {
            offpad[e] = run;
            run += (tot_c[e] + 31) & ~31;
        }
        offpad[NE] = run;

        const float invB = 1.0f / (float)NB;
        float aux = 0.0f;
        float frac[NE], avg[NE];
#pragma unroll
        for (int e = 0; e < NE; ++e) {
            frac[e] = (float)tot_c[e] * invB;
            avg[e]  = tot_f[e] * invB;
            aux += frac[e] * avg[e];
        }
        aux *= (float)NE;
        const float z   = (zet_s[0][0] + zet_s[0][1] + zet_s[0][2] + zet_s[0][3]) * invB;
        const float ent = (zet_s[1][0] + zet_s[1][1] + zet_s[1][2] + zet_s[1][3]) * invB;
        const float top = (zet_s[2][0] + zet_s[2][1] + zet_s[2][2] + zet_s[2][3]) * invB;
        const float rl  = 0.01f * aux + 0.001f * z;

        float* o = out + NB;
        o[0] = rl;
        o[1] = aux;
        o[2] = z;
#pragma unroll
        for (int e = 0; e < NE; ++e) o[3 + e]  = frac[e];
#pragma unroll
        for (int e = 0; e < NE; ++e) o[11 + e] = avg[e];
        o[19] = ent / __logf(8.0f);
        o[20] = top;
    }
}

// ---------------- Scatter rows into expert buckets (wave-aggregated atomics) ----------------
__global__ __launch_bounds__(256) void scatter_kernel(
    const int* __restrict__ idx, const int* __restrict__ offpad,
    int* __restrict__ cursors, int* __restrict__ bucket)
{
    const int b = blockIdx.x * 256 + threadIdx.x;
    const int e = idx[b];
    const int lane = threadIdx.x & 63;
#pragma unroll
    for (int ee = 0; ee < NE; ++ee) {
        unsigned long long mask = __ballot(e == ee);
        if (e == ee) {
            int leader = __ffsll((unsigned long long)mask) - 1;
            int cnt = __popcll(mask);
            int base = 0;
            if (lane == leader) base = atomicAdd(&cursors[ee], cnt);
            base = __shfl(base, leader);
            int pos = base + __popcll(mask & ((1ull << lane) - 1ull));
            bucket[offpad[ee] + pos] = b;
        }
    }
}

// ---------------- Main v4: 16 rows/block, 4 rows per 16-lane group ----------------
// wave = K-quarter (768); lane = rgrp(2b) x s(4b); acc[4][16] register block:
// each weight float4 feeds 4 rows -> weight L2 traffic 48KB/row, grid 1040 blocks
// (~16 waves/CU) for latency hiding.
__global__ __launch_bounds__(256, 4) void moe_main_kernel(
    const float* __restrict__ x, const float* __restrict__ mw,
    const float* __restrict__ mb, const float* __restrict__ l2w,
    const float* __restrict__ l2b, const float* __restrict__ ow,
    const float* __restrict__ ob, const int* __restrict__ bucket,
    const int* __restrict__ offpad, float* __restrict__ out)
{
    __shared__ int   rows_s[16];
    __shared__ int   expert_s;
    __shared__ float part_s[4][16][16];   // [wave][row][o]
    __shared__ float l1x_s[16][30];
    __shared__ float l1c15_s[16];

    const int t = threadIdx.x;
    const int slot0 = blockIdx.x * 16;
    if (t < 16) rows_s[t] = bucket[slot0 + t];
    if (t == 0) {
        int e = 0;
#pragma unroll
        for (int j = 1; j < NE; ++j) if (slot0 >= offpad[j]) e = j;
        expert_s = e;
    }
    __syncthreads();

    const int e = expert_s;
    const int wave = t >> 6;      // K-quarter
    const int lane = t & 63;
    const int rgrp = lane >> 4;   // 4 row-groups, 4 rows each
    const int s    = lane & 15;   // 16 k-slices (float4 interleave)

    const float* xp[4];
#pragma unroll
    for (int rr = 0; rr < 4; ++rr) {
        int r = rows_s[rgrp * 4 + rr];
        xp[rr] = x + (size_t)(r < 0 ? 0 : r) * ND;
    }
    const float* wb = mw + (size_t)e * NO1 * ND;

    float acc[4][16];
#pragma unroll
    for (int rr = 0; rr < 4; ++rr)
#pragma unroll
        for (int o = 0; o < 16; ++o) acc[rr][o] = 0.0f;

    const int k0 = wave * 768 + s * 4;
#pragma unroll 2
    for (int step = 0; step < 12; ++step) {
        const int kb = k0 + step * 64;
        float4 xr[4];
#pragma unroll
        for (int rr = 0; rr < 4; ++rr) xr[rr] = *(const float4*)(xp[rr] + kb);
        const float* wk = wb + kb;
#pragma unroll
        for (int o = 0; o < 16; ++o) {
            const float4 w = *(const float4*)(wk + (size_t)o * ND);
#pragma unroll
            for (int rr = 0; rr < 4; ++rr) {
                float a = acc[rr][o];
                a = fmaf(xr[rr].x, w.x, a);
                a = fmaf(xr[rr].y, w.y, a);
                a = fmaf(xr[rr].z, w.z, a);
                a = fmaf(xr[rr].w, w.w, a);
                acc[rr][o] = a;
            }
        }
    }

    // reduce over s (16 k-slices within each row-group)
#pragma unroll
    for (int rr = 0; rr < 4; ++rr)
#pragma unroll
        for (int o = 0; o < 16; ++o) {
            float a = acc[rr][o];
            a += __shfl_xor(a, 1);
            a += __shfl_xor(a, 2);
            a += __shfl_xor(a, 4);
            a += __shfl_xor(a, 8);
            acc[rr][o] = a;
        }
    if (s == 0) {
#pragma unroll
        for (int rr = 0; rr < 4; ++rr)
#pragma unroll
            for (int o = 0; o < 16; ++o)
                part_s[wave][rgrp * 4 + rr][o] = acc[rr][o];
    }
    __syncthreads();

    // ---- tail: l1 activation, l2, l3; 16 threads per row ----
    const int r = t >> 4;   // row 0..15
    const int q = t & 15;   // 16 threads per row
    const int rowb = rows_s[r];

    {
        const int o = q;
        float v = part_s[0][r][o] + part_s[1][r][o] + part_s[2][r][o]
                + part_s[3][r][o] + mb[e * NO1 + o];
        if (o < 15) {
            l1x_s[r][o]      = clamp01(v * v * (255.0f / 256.0f));
            l1x_s[r][o + 15] = clamp01(v);
        } else {
            l1c15_s[r] = v;
        }
    }
    __syncthreads();

    float pacc = 0.0f;
#pragma unroll
    for (int oo = 0; oo < 2; ++oo) {
        const int o2 = q + oo * 16;
        float a2 = l2b[e * NL3 + o2];
        const float* w2r = l2w + (size_t)e * NL3 * NL2D + o2 * NL2D;
#pragma unroll
        for (int i = 0; i < NL2D; ++i) a2 = fmaf(l1x_s[r][i], w2r[i], a2);
        a2 = clamp01(a2);
        pacc = fmaf(a2, ow[e * NL3 + o2], pacc);
    }
    pacc += __shfl_xor(pacc, 1);
    pacc += __shfl_xor(pacc, 2);
    pacc += __shfl_xor(pacc, 4);
    pacc += __shfl_xor(pacc, 8);

    if (q == 0 && rowb >= 0) {
        out[rowb] = pacc + ob[e] + l1c15_s[r];
    }
}

extern "C" void kernel_launch(void* const* d_in, const int* in_sizes, int n_in,
                              void* d_out, int out_size, void* d_ws, size_t ws_size,
                              hipStream_t stream)
{
    const float* x    = (const float*)d_in[0];
    const float* rin  = (const float*)d_in[1];
    const float* rw   = (const float*)d_in[2];
    const float* rb   = (const float*)d_in[3];
    const float* l1w  = (const float*)d_in[4];
    const float* l1b  = (const float*)d_in[5];
    const float* l1fw = (const float*)d_in[6];
    const float* l1fb = (const float*)d_in[7];
    const float* l2w  = (const float*)d_in[8];
    const float* l2b  = (const float*)d_in[9];
    const float* ow   = (const float*)d_in[10];
    const float* ob   = (const float*)d_in[11];
    float* out = (float*)d_out;

    char* ws = (char*)d_ws;
    int*   cursors = (int*)(ws + WS_CURSORS);
    int*   offpad  = (int*)(ws + WS_OFFPAD);
    int*   idx     = (int*)(ws + WS_IDX);
    int*   bucket  = (int*)(ws + WS_BUCKET);
    float* mb      = (float*)(ws + WS_MB);
    float* mw      = (float*)(ws + WS_MW);
    int*   blk_cnt  = (int*)(ws + WS_BLK_CNT);
    float* blk_sump = (float*)(ws + WS_BLK_SUMP);
    float* blk_z    = (float*)(ws + WS_BLK_Z);
    float* blk_ent  = (float*)(ws + WS_BLK_ENT);
    float* blk_top  = (float*)(ws + WS_BLK_TOP);

    hipMemsetAsync(ws, 0, 256, stream);
    hipMemsetAsync(ws + WS_BUCKET, 0xFF, (size_t)(NB + 256) * 4, stream);

    router2_kernel<<<NB / 64, 256, 0, stream>>>(rin, rw, rb, idx, blk_cnt, blk_sump,
                                                blk_z, blk_ent, blk_top);
    merge_kernel<<<(NE * NO1 * ND + 255) / 256, 256, 0, stream>>>(l1w, l1b, l1fw, l1fb, mw, mb);
    finalize2_kernel<<<1, 256, 0, stream>>>(blk_cnt, blk_sump, blk_z, blk_ent, blk_top,
                                            offpad, out);
    scatter_kernel<<<NB / 256, 256, 0, stream>>>(idx, offpad, cursors, bucket);
    moe_main_kernel<<<(NB + 256) / 16, 256, 0, stream>>>(x, mw, mb, l2w, l2b, ow, ob,
                                                         bucket, offpad, out);
}

// Round 5
// 140.915 us; speedup vs baseline: 1.3144x; 1.2902x over previous
//
#include <hip/hip_runtime.h>

constexpr int NB  = 16384;  // batch
constexpr int ND  = 3072;   // D
constexpr int NR  = 256;    // R
constexpr int NE  = 8;      // experts
constexpr int NO1 = 16;     // L2+1 outputs of l1
constexpr int NL2D = 30;    // 2*L2
constexpr int NL3 = 32;     // L3

// ---- workspace layout (bytes) ----
constexpr size_t WS_CURSORS = 32;     // int[8]
constexpr size_t WS_OFFPAD  = 128;    // int[9]
constexpr size_t WS_IDX     = 256;                    // int[NB]
constexpr size_t WS_BUCKET  = WS_IDX + (size_t)NB*4;  // int[NB+256]
constexpr size_t WS_MB      = WS_BUCKET + (size_t)(NB+256)*4; // float[128]
constexpr size_t WS_MW      = WS_MB + 512;            // float[128*3072]
constexpr size_t WS_BLK_CNT  = WS_MW + (size_t)128*3072*4;   // int[256*8]
constexpr size_t WS_BLK_SUMP = WS_BLK_CNT + 8192;            // float[256*8]
constexpr size_t WS_BLK_Z    = WS_BLK_SUMP + 8192;           // float[256]
constexpr size_t WS_BLK_ENT  = WS_BLK_Z + 1024;              // float[256]
constexpr size_t WS_BLK_TOP  = WS_BLK_ENT + 1024;            // float[256]

__device__ __forceinline__ float clamp01(float v) { return fminf(fmaxf(v, 0.0f), 1.0f); }

// ---------------- Router v2: 64 rows/block, 4 threads/row ----------------
__global__ __launch_bounds__(256) void router2_kernel(
    const float* __restrict__ rin, const float* __restrict__ rw,
    const float* __restrict__ rb, int* __restrict__ idx,
    int* __restrict__ blk_cnt, float* __restrict__ blk_sump,
    float* __restrict__ blk_z, float* __restrict__ blk_ent, float* __restrict__ blk_top)
{
    __shared__ float w_s[NE][NR];          // 8 KB
    __shared__ float red_f[4][11];
    __shared__ int   red_c[4][8];

    const int t = threadIdx.x;
    {
        const float4* src = (const float4*)rw;
        float4* dst = (float4*)&w_s[0][0];
        dst[t]       = src[t];
        dst[t + 256] = src[t + 256];
    }
    __syncthreads();

    const int q  = t & 3;          // quarter of the row (64 elems each)
    const int rr = t >> 2;         // row within block, 0..63
    const int b  = blockIdx.x * 64 + rr;
    const float* rp = rin + (size_t)b * NR + q * 64;

    float acc[NE];
#pragma unroll
    for (int e = 0; e < NE; ++e) acc[e] = 0.0f;

#pragma unroll
    for (int c = 0; c < 16; ++c) {
        const float4 xv = *(const float4*)(rp + c * 4);
#pragma unroll
        for (int e = 0; e < NE; ++e) {
            const float4 wv = *(const float4*)(&w_s[e][q * 64 + c * 4]);
            acc[e] = fmaf(xv.x, wv.x, acc[e]);
            acc[e] = fmaf(xv.y, wv.y, acc[e]);
            acc[e] = fmaf(xv.z, wv.z, acc[e]);
            acc[e] = fmaf(xv.w, wv.w, acc[e]);
        }
    }
    float lg[NE];
#pragma unroll
    for (int e = 0; e < NE; ++e) {
        float v = acc[e];
        v += __shfl_xor(v, 1);
        v += __shfl_xor(v, 2);
        lg[e] = v + rb[e];
    }

    float m = lg[0]; int am = 0;
#pragma unroll
    for (int e = 1; e < NE; ++e) { if (lg[e] > m) { m = lg[e]; am = e; } }
    float p[NE]; float ssum = 0.0f;
#pragma unroll
    for (int e = 0; e < NE; ++e) { p[e] = __expf(lg[e] - m); ssum += p[e]; }
    const float inv = 1.0f / ssum;
    const float lse = m + __logf(ssum);

    const bool active = (q == 0);
    float sv[11];
    float ent = 0.0f, top = 0.0f;
#pragma unroll
    for (int e = 0; e < NE; ++e) {
        const float pj = p[e] * inv;
        sv[e] = pj;
        ent -= pj * __logf(fmaxf(pj, 1e-9f));
        top = fmaxf(top, pj);
    }
    sv[8] = lse * lse;
    sv[9] = ent;
    sv[10] = top;
    if (!active) {
#pragma unroll
        for (int i = 0; i < 11; ++i) sv[i] = 0.0f;
    }
    if (active) idx[b] = am;

#pragma unroll
    for (int i = 0; i < 11; ++i) {
        float v = sv[i];
        v += __shfl_xor(v, 4);
        v += __shfl_xor(v, 8);
        v += __shfl_xor(v, 16);
        v += __shfl_xor(v, 32);
        sv[i] = v;
    }
    int cnt[NE];
#pragma unroll
    for (int j = 0; j < NE; ++j) {
        unsigned long long mk = __ballot(active && (am == j));
        cnt[j] = __popcll(mk);
    }

    const int wave = t >> 6;
    if ((t & 63) == 0) {
#pragma unroll
        for (int i = 0; i < 11; ++i) red_f[wave][i] = sv[i];
#pragma unroll
        for (int j = 0; j < NE; ++j) red_c[wave][j] = cnt[j];
    }
    __syncthreads();

    const int bid = blockIdx.x;
    if (t < 8) {
        blk_sump[bid * 8 + t] = red_f[0][t] + red_f[1][t] + red_f[2][t] + red_f[3][t];
        blk_cnt [bid * 8 + t] = red_c[0][t] + red_c[1][t] + red_c[2][t] + red_c[3][t];
    } else if (t == 8) {
        blk_z[bid]   = red_f[0][8] + red_f[1][8] + red_f[2][8] + red_f[3][8];
    } else if (t == 9) {
        blk_ent[bid] = red_f[0][9] + red_f[1][9] + red_f[2][9] + red_f[3][9];
    } else if (t == 10) {
        blk_top[bid] = red_f[0][10] + red_f[1][10] + red_f[2][10] + red_f[3][10];
    }
}

// ---------------- Merge l1 weights: merged = l1_w + tile(l1f_w) ----------------
__global__ __launch_bounds__(256) void merge_kernel(
    const float* __restrict__ l1w, const float* __restrict__ l1b,
    const float* __restrict__ l1fw, const float* __restrict__ l1fb,
    float* __restrict__ mw, float* __restrict__ mb)
{
    const int i = blockIdx.x * 256 + threadIdx.x;
    const int total = NE * NO1 * ND;   // 128*3072
    if (i < total) {
        mw[i] = l1w[i] + l1fw[i % (NO1 * ND)];
    }
    if (i < NE * NO1) {
        mb[i] = l1b[i] + l1fb[i & (NO1 - 1)];
    }
}

// ---------------- Finalize v2: reduce 256 per-block partials ----------------
__global__ __launch_bounds__(256) void finalize2_kernel(
    const int* __restrict__ blk_cnt, const float* __restrict__ blk_sump,
    const float* __restrict__ blk_z, const float* __restrict__ blk_ent,
    const float* __restrict__ blk_top, int* __restrict__ offpad,
    float* __restrict__ out)
{
    __shared__ float ps_s[32][8];
    __shared__ int   pc_s[32][8];
    __shared__ float zet_s[3][4];
    __shared__ float tot_f[8];
    __shared__ int   tot_c[8];

    const int t = threadIdx.x;
    {
        const int e = t & 7, g = t >> 3;
        float ps = 0.0f; int pc = 0;
#pragma unroll
        for (int k = 0; k < 8; ++k) {
            const int bb = g * 8 + k;
            ps += blk_sump[bb * 8 + e];
            pc += blk_cnt [bb * 8 + e];
        }
        ps_s[g][e] = ps;
        pc_s[g][e] = pc;
    }
    {
        float z = blk_z[t], en = blk_ent[t], tp = blk_top[t];
#pragma unroll
        for (int o = 1; o < 64; o <<= 1) {
            z  += __shfl_xor(z, o);
            en += __shfl_xor(en, o);
            tp += __shfl_xor(tp, o);
        }
        const int wave = t >> 6;
        if ((t & 63) == 0) { zet_s[0][wave] = z; zet_s[1][wave] = en; zet_s[2][wave] = tp; }
    }
    __syncthreads();

    if (t < 8) {
        float s = 0.0f; int c = 0;
        for (int g = 0; g < 32; ++g) { s += ps_s[g][t]; c += pc_s[g][t]; }
        tot_f[t] = s; tot_c[t] = c;
    }
    __syncthreads();

    if (t == 0) {
        int run = 0;
#pragma unroll
        for (int e = 0; e < NE; ++e) {
            offpad[e] = run;
            run += (tot_c[e] + 31) & ~31;
        }
        offpad[NE] = run;

        const float invB = 1.0f / (float)NB;
        float aux = 0.0f;
        float frac[NE], avg[NE];
#pragma unroll
        for (int e = 0; e < NE; ++e) {
            frac[e] = (float)tot_c[e] * invB;
            avg[e]  = tot_f[e] * invB;
            aux += frac[e] * avg[e];
        }
        aux *= (float)NE;
        const float z   = (zet_s[0][0] + zet_s[0][1] + zet_s[0][2] + zet_s[0][3]) * invB;
        const float ent = (zet_s[1][0] + zet_s[1][1] + zet_s[1][2] + zet_s[1][3]) * invB;
        const float top = (zet_s[2][0] + zet_s[2][1] + zet_s[2][2] + zet_s[2][3]) * invB;
        const float rl  = 0.01f * aux + 0.001f * z;

        float* o = out + NB;
        o[0] = rl;
        o[1] = aux;
        o[2] = z;
#pragma unroll
        for (int e = 0; e < NE; ++e) o[3 + e]  = frac[e];
#pragma unroll
        for (int e = 0; e < NE; ++e) o[11 + e] = avg[e];
        o[19] = ent / __logf(8.0f);
        o[20] = top;
    }
}

// ---------------- Scatter rows into expert buckets (wave-aggregated atomics) ----------------
__global__ __launch_bounds__(256) void scatter_kernel(
    const int* __restrict__ idx, const int* __restrict__ offpad,
    int* __restrict__ cursors, int* __restrict__ bucket)
{
    const int b = blockIdx.x * 256 + threadIdx.x;
    const int e = idx[b];
    const int lane = threadIdx.x & 63;
#pragma unroll
    for (int ee = 0; ee < NE; ++ee) {
        unsigned long long mask = __ballot(e == ee);
        if (e == ee) {
            int leader = __ffsll((unsigned long long)mask) - 1;
            int cnt = __popcll(mask);
            int base = 0;
            if (lane == leader) base = atomicAdd(&cursors[ee], cnt);
            base = __shfl(base, leader);
            int pos = base + __popcll(mask & ((1ull << lane) - 1ull));
            bucket[offpad[ee] + pos] = b;
        }
    }
}

// ---------------- Main v5: 16 rows/block, round-2 inner structure ----------------
// wave = K-quarter (768 k each); lane = rgrp(2b) x s(4b); 4 rows per 16-lane
// group, acc[4][16] register block (each weight float4 feeds 4 rows).
// NO min-waves launch bound: round 4 showed (256,4) clamps VGPR to 64 and
// spills acc to scratch (WRITE_SIZE 95 MB). VGPR ~80 <= 128 still allows
// 4 waves/SIMD; grid 1040 blocks ~= 4 blocks/CU.
__global__ __launch_bounds__(256) void moe_main_kernel(
    const float* __restrict__ x, const float* __restrict__ mw,
    const float* __restrict__ mb, const float* __restrict__ l2w,
    const float* __restrict__ l2b, const float* __restrict__ ow,
    const float* __restrict__ ob, const int* __restrict__ bucket,
    const int* __restrict__ offpad, float* __restrict__ out)
{
    __shared__ int   rows_s[16];
    __shared__ int   expert_s;
    __shared__ float part_s[4][16][16];   // [wave][row][o]
    __shared__ float l1x_s[16][30];
    __shared__ float l1c15_s[16];

    const int t = threadIdx.x;
    const int slot0 = blockIdx.x * 16;
    if (t < 16) rows_s[t] = bucket[slot0 + t];
    if (t == 0) {
        int e = 0;
#pragma unroll
        for (int j = 1; j < NE; ++j) if (slot0 >= offpad[j]) e = j;
        expert_s = e;
    }
    __syncthreads();

    const int e = expert_s;
    const int wave = t >> 6;      // K-quarter
    const int lane = t & 63;
    const int rgrp = lane >> 4;   // 4 row-groups, 4 rows each
    const int s    = lane & 15;   // 16 k-slices (float4 interleave)

    const float* xp[4];
#pragma unroll
    for (int rr = 0; rr < 4; ++rr) {
        int r = rows_s[rgrp * 4 + rr];
        xp[rr] = x + (size_t)(r < 0 ? 0 : r) * ND;
    }
    const float* wb = mw + (size_t)e * NO1 * ND;

    float acc[4][16];
#pragma unroll
    for (int rr = 0; rr < 4; ++rr)
#pragma unroll
        for (int o = 0; o < 16; ++o) acc[rr][o] = 0.0f;

    const int k0 = wave * 768 + s * 4;
    for (int step = 0; step < 12; ++step) {
        const int kb = k0 + step * 64;
        float4 xr[4];
#pragma unroll
        for (int rr = 0; rr < 4; ++rr) xr[rr] = *(const float4*)(xp[rr] + kb);
        const float* wk = wb + kb;
#pragma unroll
        for (int o = 0; o < 16; ++o) {
            const float4 w = *(const float4*)(wk + (size_t)o * ND);
#pragma unroll
            for (int rr = 0; rr < 4; ++rr) {
                float a = acc[rr][o];
                a = fmaf(xr[rr].x, w.x, a);
                a = fmaf(xr[rr].y, w.y, a);
                a = fmaf(xr[rr].z, w.z, a);
                a = fmaf(xr[rr].w, w.w, a);
                acc[rr][o] = a;
            }
        }
    }

    // reduce over s (16 k-slices within each row-group)
#pragma unroll
    for (int rr = 0; rr < 4; ++rr)
#pragma unroll
        for (int o = 0; o < 16; ++o) {
            float a = acc[rr][o];
            a += __shfl_xor(a, 1);
            a += __shfl_xor(a, 2);
            a += __shfl_xor(a, 4);
            a += __shfl_xor(a, 8);
            acc[rr][o] = a;
        }
    if (s == 0) {
#pragma unroll
        for (int rr = 0; rr < 4; ++rr)
#pragma unroll
            for (int o = 0; o < 16; ++o)
                part_s[wave][rgrp * 4 + rr][o] = acc[rr][o];
    }
    __syncthreads();

    // ---- tail: l1 activation, l2, l3; 16 threads per row ----
    const int r = t >> 4;   // row 0..15
    const int q = t & 15;   // 16 threads per row
    const int rowb = rows_s[r];

    {
        const int o = q;
        float v = part_s[0][r][o] + part_s[1][r][o] + part_s[2][r][o]
                + part_s[3][r][o] + mb[e * NO1 + o];
        if (o < 15) {
            l1x_s[r][o]      = clamp01(v * v * (255.0f / 256.0f));
            l1x_s[r][o + 15] = clamp01(v);
        } else {
            l1c15_s[r] = v;
        }
    }
    __syncthreads();

    float pacc = 0.0f;
#pragma unroll
    for (int oo = 0; oo < 2; ++oo) {
        const int o2 = q + oo * 16;
        float a2 = l2b[e * NL3 + o2];
        const float* w2r = l2w + (size_t)e * NL3 * NL2D + o2 * NL2D;
#pragma unroll
        for (int i = 0; i < NL2D; ++i) a2 = fmaf(l1x_s[r][i], w2r[i], a2);
        a2 = clamp01(a2);
        pacc = fmaf(a2, ow[e * NL3 + o2], pacc);
    }
    pacc += __shfl_xor(pacc, 1);
    pacc += __shfl_xor(pacc, 2);
    pacc += __shfl_xor(pacc, 4);
    pacc += __shfl_xor(pacc, 8);

    if (q == 0 && rowb >= 0) {
        out[rowb] = pacc + ob[e] + l1c15_s[r];
    }
}

extern "C" void kernel_launch(void* const* d_in, const int* in_sizes, int n_in,
                              void* d_out, int out_size, void* d_ws, size_t ws_size,
                              hipStream_t stream)
{
    const float* x    = (const float*)d_in[0];
    const float* rin  = (const float*)d_in[1];
    const float* rw   = (const float*)d_in[2];
    const float* rb   = (const float*)d_in[3];
    const float* l1w  = (const float*)d_in[4];
    const float* l1b  = (const float*)d_in[5];
    const float* l1fw = (const float*)d_in[6];
    const float* l1fb = (const float*)d_in[7];
    const float* l2w  = (const float*)d_in[8];
    const float* l2b  = (const float*)d_in[9];
    const float* ow   = (const float*)d_in[10];
    const float* ob   = (const float*)d_in[11];
    float* out = (float*)d_out;

    char* ws = (char*)d_ws;
    int*   cursors = (int*)(ws + WS_CURSORS);
    int*   offpad  = (int*)(ws + WS_OFFPAD);
    int*   idx     = (int*)(ws + WS_IDX);
    int*   bucket  = (int*)(ws + WS_BUCKET);
    float* mb      = (float*)(ws + WS_MB);
    float* mw      = (float*)(ws + WS_MW);
    int*   blk_cnt  = (int*)(ws + WS_BLK_CNT);
    float* blk_sump = (float*)(ws + WS_BLK_SUMP);
    float* blk_z    = (float*)(ws + WS_BLK_Z);
    float* blk_ent  = (float*)(ws + WS_BLK_ENT);
    float* blk_top  = (float*)(ws + WS_BLK_TOP);

    hipMemsetAsync(ws, 0, 256, stream);
    hipMemsetAsync(ws + WS_BUCKET, 0xFF, (size_t)(NB + 256) * 4, stream);

    router2_kernel<<<NB / 64, 256, 0, stream>>>(rin, rw, rb, idx, blk_cnt, blk_sump,
                                                blk_z, blk_ent, blk_top);
    merge_kernel<<<(NE * NO1 * ND + 255) / 256, 256, 0, stream>>>(l1w, l1b, l1fw, l1fb, mw, mb);
    finalize2_kernel<<<1, 256, 0, stream>>>(blk_cnt, blk_sump, blk_z, blk_ent, blk_top,
                                            offpad, out);
    scatter_kernel<<<NB / 256, 256, 0, stream>>>(idx, offpad, cursors, bucket);
    moe_main_kernel<<<(NB + 256) / 16, 256, 0, stream>>>(x, mw, mb, l2w, l2b, ow, ob,
                                                         bucket, offpad, out);
}

// Round 6
// 139.077 us; speedup vs baseline: 1.3318x; 1.0132x over previous
//
#include <hip/hip_runtime.h>

constexpr int NB  = 16384;  // batch
constexpr int ND  = 3072;   // D
constexpr int NR  = 256;    // R
constexpr int NE  = 8;      // experts
constexpr int NO1 = 16;     // L2+1 outputs of l1
constexpr int NL2D = 30;    // 2*L2
constexpr int NL3 = 32;     // L3

// ---- workspace layout (bytes) ----
constexpr size_t WS_CURSORS = 32;     // int[8]
constexpr size_t WS_OFFPAD  = 128;    // int[9]
constexpr size_t WS_IDX     = 256;                    // int[NB]
constexpr size_t WS_BUCKET  = WS_IDX + (size_t)NB*4;  // int[NB+256]
constexpr size_t WS_MB      = WS_BUCKET + (size_t)(NB+256)*4; // float[128]
constexpr size_t WS_MW      = WS_MB + 512;            // float[128*3072]
constexpr size_t WS_BLK_CNT  = WS_MW + (size_t)128*3072*4;   // int[256*8]
constexpr size_t WS_BLK_SUMP = WS_BLK_CNT + 8192;            // float[256*8]
constexpr size_t WS_BLK_Z    = WS_BLK_SUMP + 8192;           // float[256]
constexpr size_t WS_BLK_ENT  = WS_BLK_Z + 1024;              // float[256]
constexpr size_t WS_BLK_TOP  = WS_BLK_ENT + 1024;            // float[256]

__device__ __forceinline__ float clamp01(float v) { return fminf(fmaxf(v, 0.0f), 1.0f); }

// ---------------- Router v2: 64 rows/block, 4 threads/row ----------------
__global__ __launch_bounds__(256) void router2_kernel(
    const float* __restrict__ rin, const float* __restrict__ rw,
    const float* __restrict__ rb, int* __restrict__ idx,
    int* __restrict__ blk_cnt, float* __restrict__ blk_sump,
    float* __restrict__ blk_z, float* __restrict__ blk_ent, float* __restrict__ blk_top)
{
    __shared__ float w_s[NE][NR];          // 8 KB
    __shared__ float red_f[4][11];
    __shared__ int   red_c[4][8];

    const int t = threadIdx.x;
    {
        const float4* src = (const float4*)rw;
        float4* dst = (float4*)&w_s[0][0];
        dst[t]       = src[t];
        dst[t + 256] = src[t + 256];
    }
    __syncthreads();

    const int q  = t & 3;          // quarter of the row (64 elems each)
    const int rr = t >> 2;         // row within block, 0..63
    const int b  = blockIdx.x * 64 + rr;
    const float* rp = rin + (size_t)b * NR + q * 64;

    float acc[NE];
#pragma unroll
    for (int e = 0; e < NE; ++e) acc[e] = 0.0f;

#pragma unroll
    for (int c = 0; c < 16; ++c) {
        const float4 xv = *(const float4*)(rp + c * 4);
#pragma unroll
        for (int e = 0; e < NE; ++e) {
            const float4 wv = *(const float4*)(&w_s[e][q * 64 + c * 4]);
            acc[e] = fmaf(xv.x, wv.x, acc[e]);
            acc[e] = fmaf(xv.y, wv.y, acc[e]);
            acc[e] = fmaf(xv.z, wv.z, acc[e]);
            acc[e] = fmaf(xv.w, wv.w, acc[e]);
        }
    }
    float lg[NE];
#pragma unroll
    for (int e = 0; e < NE; ++e) {
        float v = acc[e];
        v += __shfl_xor(v, 1);
        v += __shfl_xor(v, 2);
        lg[e] = v + rb[e];
    }

    float m = lg[0]; int am = 0;
#pragma unroll
    for (int e = 1; e < NE; ++e) { if (lg[e] > m) { m = lg[e]; am = e; } }
    float p[NE]; float ssum = 0.0f;
#pragma unroll
    for (int e = 0; e < NE; ++e) { p[e] = __expf(lg[e] - m); ssum += p[e]; }
    const float inv = 1.0f / ssum;
    const float lse = m + __logf(ssum);

    const bool active = (q == 0);
    float sv[11];
    float ent = 0.0f, top = 0.0f;
#pragma unroll
    for (int e = 0; e < NE; ++e) {
        const float pj = p[e] * inv;
        sv[e] = pj;
        ent -= pj * __logf(fmaxf(pj, 1e-9f));
        top = fmaxf(top, pj);
    }
    sv[8] = lse * lse;
    sv[9] = ent;
    sv[10] = top;
    if (!active) {
#pragma unroll
        for (int i = 0; i < 11; ++i) sv[i] = 0.0f;
    }
    if (active) idx[b] = am;

#pragma unroll
    for (int i = 0; i < 11; ++i) {
        float v = sv[i];
        v += __shfl_xor(v, 4);
        v += __shfl_xor(v, 8);
        v += __shfl_xor(v, 16);
        v += __shfl_xor(v, 32);
        sv[i] = v;
    }
    int cnt[NE];
#pragma unroll
    for (int j = 0; j < NE; ++j) {
        unsigned long long mk = __ballot(active && (am == j));
        cnt[j] = __popcll(mk);
    }

    const int wave = t >> 6;
    if ((t & 63) == 0) {
#pragma unroll
        for (int i = 0; i < 11; ++i) red_f[wave][i] = sv[i];
#pragma unroll
        for (int j = 0; j < NE; ++j) red_c[wave][j] = cnt[j];
    }
    __syncthreads();

    const int bid = blockIdx.x;
    if (t < 8) {
        blk_sump[bid * 8 + t] = red_f[0][t] + red_f[1][t] + red_f[2][t] + red_f[3][t];
        blk_cnt [bid * 8 + t] = red_c[0][t] + red_c[1][t] + red_c[2][t] + red_c[3][t];
    } else if (t == 8) {
        blk_z[bid]   = red_f[0][8] + red_f[1][8] + red_f[2][8] + red_f[3][8];
    } else if (t == 9) {
        blk_ent[bid] = red_f[0][9] + red_f[1][9] + red_f[2][9] + red_f[3][9];
    } else if (t == 10) {
        blk_top[bid] = red_f[0][10] + red_f[1][10] + red_f[2][10] + red_f[3][10];
    }
}

// ---------------- Merge l1 weights: merged = l1_w + tile(l1f_w) ----------------
__global__ __launch_bounds__(256) void merge_kernel(
    const float* __restrict__ l1w, const float* __restrict__ l1b,
    const float* __restrict__ l1fw, const float* __restrict__ l1fb,
    float* __restrict__ mw, float* __restrict__ mb)
{
    const int i = blockIdx.x * 256 + threadIdx.x;
    const int total = NE * NO1 * ND;   // 128*3072
    if (i < total) {
        mw[i] = l1w[i] + l1fw[i % (NO1 * ND)];
    }
    if (i < NE * NO1) {
        mb[i] = l1b[i] + l1fb[i & (NO1 - 1)];
    }
}

// ---------------- Finalize v2: reduce 256 per-block partials ----------------
__global__ __launch_bounds__(256) void finalize2_kernel(
    const int* __restrict__ blk_cnt, const float* __restrict__ blk_sump,
    const float* __restrict__ blk_z, const float* __restrict__ blk_ent,
    const float* __restrict__ blk_top, int* __restrict__ offpad,
    float* __restrict__ out)
{
    __shared__ float ps_s[32][8];
    __shared__ int   pc_s[32][8];
    __shared__ float zet_s[3][4];
    __shared__ float tot_f[8];
    __shared__ int   tot_c[8];

    const int t = threadIdx.x;
    {
        const int e = t & 7, g = t >> 3;
        float ps = 0.0f; int pc = 0;
#pragma unroll
        for (int k = 0; k < 8; ++k) {
            const int bb = g * 8 + k;
            ps += blk_sump[bb * 8 + e];
            pc += blk_cnt [bb * 8 + e];
        }
        ps_s[g][e] = ps;
        pc_s[g][e] = pc;
    }
    {
        float z = blk_z[t], en = blk_ent[t], tp = blk_top[t];
#pragma unroll
        for (int o = 1; o < 64; o <<= 1) {
            z  += __shfl_xor(z, o);
            en += __shfl_xor(en, o);
            tp += __shfl_xor(tp, o);
        }
        const int wave = t >> 6;
        if ((t & 63) == 0) { zet_s[0][wave] = z; zet_s[1][wave] = en; zet_s[2][wave] = tp; }
    }
    __syncthreads();

    if (t < 8) {
        float s = 0.0f; int c = 0;
        for (int g = 0; g < 32; ++g) { s += ps_s[g][t]; c += pc_s[g][t]; }
        tot_f[t] = s; tot_c[t] = c;
    }
    __syncthreads();

    if (t == 0) {
        int run = 0;
#pragma unroll
        for (int e = 0; e < NE; ++e) {
            offpad[e] = run;
            run += (tot_c[e] + 31) & ~31;
        }
        offpad[NE] = run;

        const float invB = 1.0f / (float)NB;
        float aux = 0.0f;
        float frac[NE], avg[NE];
#pragma unroll
        for (int e = 0; e < NE; ++e) {
            frac[e] = (float)tot_c[e] * invB;
            avg[e]  = tot_f[e] * invB;
            aux += frac[e] * avg[e];
        }
        aux *= (float)NE;
        const float z   = (zet_s[0][0] + zet_s[0][1] + zet_s[0][2] + zet_s[0][3]) * invB;
        const float ent = (zet_s[1][0] + zet_s[1][1] + zet_s[1][2] + zet_s[1][3]) * invB;
        const float top = (zet_s[2][0] + zet_s[2][1] + zet_s[2][2] + zet_s[2][3]) * invB;
        const float rl  = 0.01f * aux + 0.001f * z;

        float* o = out + NB;
        o[0] = rl;
        o[1] = aux;
        o[2] = z;
#pragma unroll
        for (int e = 0; e < NE; ++e) o[3 + e]  = frac[e];
#pragma unroll
        for (int e = 0; e < NE; ++e) o[11 + e] = avg[e];
        o[19] = ent / __logf(8.0f);
        o[20] = top;
    }
}

// ---------------- Scatter rows into expert buckets (wave-aggregated atomics) ----------------
__global__ __launch_bounds__(256) void scatter_kernel(
    const int* __restrict__ idx, const int* __restrict__ offpad,
    int* __restrict__ cursors, int* __restrict__ bucket)
{
    const int b = blockIdx.x * 256 + threadIdx.x;
    const int e = idx[b];
    const int lane = threadIdx.x & 63;
#pragma unroll
    for (int ee = 0; ee < NE; ++ee) {
        unsigned long long mask = __ballot(e == ee);
        if (e == ee) {
            int leader = __ffsll((unsigned long long)mask) - 1;
            int cnt = __popcll(mask);
            int base = 0;
            if (lane == leader) base = atomicAdd(&cursors[ee], cnt);
            base = __shfl(base, leader);
            int pos = base + __popcll(mask & ((1ull << lane) - 1ull));
            bucket[offpad[ee] + pos] = b;
        }
    }
}

// ---------------- Main v6: 8 rows/block, 4 rows per 32-lane group ----------------
// Grid 2080 blocks (~8/CU queued, 4 co-resident at VGPR~72 -> ~50% occupancy),
// keeping the proven acc[4][16] register block (each weight float4 feeds 4 rows;
// 20 loads per 512 VALU-cycles). Weight L2 traffic 2080*192KB = 400 MB (~12 us).
// NO min-waves bound (round 4: (256,4) clamps VGPR to 64 -> scratch spill).
__global__ __launch_bounds__(256) void moe_main_kernel(
    const float* __restrict__ x, const float* __restrict__ mw,
    const float* __restrict__ mb, const float* __restrict__ l2w,
    const float* __restrict__ l2b, const float* __restrict__ ow,
    const float* __restrict__ ob, const int* __restrict__ bucket,
    const int* __restrict__ offpad, float* __restrict__ out)
{
    __shared__ int   rows_s[8];
    __shared__ int   expert_s;
    __shared__ float part_s[4][8][16];   // [wave][row][o]
    __shared__ float l1x_s[8][30];
    __shared__ float l1c15_s[8];

    const int t = threadIdx.x;
    const int slot0 = blockIdx.x * 8;
    if (t < 8) rows_s[t] = bucket[slot0 + t];
    if (t == 0) {
        int e = 0;
#pragma unroll
        for (int j = 1; j < NE; ++j) if (slot0 >= offpad[j]) e = j;
        expert_s = e;
    }
    __syncthreads();

    const int e = expert_s;
    const int wave = t >> 6;      // K-quarter
    const int lane = t & 63;
    const int rgrp = lane >> 5;   // 2 row-groups, 4 rows each
    const int s    = lane & 31;   // 32 k-slices (float4 interleave)

    const float* xp[4];
#pragma unroll
    for (int rr = 0; rr < 4; ++rr) {
        int r = rows_s[rgrp * 4 + rr];
        xp[rr] = x + (size_t)(r < 0 ? 0 : r) * ND;
    }
    const float* wb = mw + (size_t)e * NO1 * ND;

    float acc[4][16];
#pragma unroll
    for (int rr = 0; rr < 4; ++rr)
#pragma unroll
        for (int o = 0; o < 16; ++o) acc[rr][o] = 0.0f;

    const int k0 = wave * 768 + s * 4;
    for (int step = 0; step < 6; ++step) {
        const int kb = k0 + step * 128;
        float4 xr[4];
#pragma unroll
        for (int rr = 0; rr < 4; ++rr) xr[rr] = *(const float4*)(xp[rr] + kb);
        const float* wk = wb + kb;
#pragma unroll
        for (int o = 0; o < 16; ++o) {
            const float4 w = *(const float4*)(wk + (size_t)o * ND);
#pragma unroll
            for (int rr = 0; rr < 4; ++rr) {
                float a = acc[rr][o];
                a = fmaf(xr[rr].x, w.x, a);
                a = fmaf(xr[rr].y, w.y, a);
                a = fmaf(xr[rr].z, w.z, a);
                a = fmaf(xr[rr].w, w.w, a);
                acc[rr][o] = a;
            }
        }
    }

    // reduce over s (32 k-slices within each row-group)
#pragma unroll
    for (int rr = 0; rr < 4; ++rr)
#pragma unroll
        for (int o = 0; o < 16; ++o) {
            float a = acc[rr][o];
            a += __shfl_xor(a, 1);
            a += __shfl_xor(a, 2);
            a += __shfl_xor(a, 4);
            a += __shfl_xor(a, 8);
            a += __shfl_xor(a, 16);
            acc[rr][o] = a;
        }
    if (s == 0) {
#pragma unroll
        for (int rr = 0; rr < 4; ++rr)
#pragma unroll
            for (int o = 0; o < 16; ++o)
                part_s[wave][rgrp * 4 + rr][o] = acc[rr][o];
    }
    __syncthreads();

    // ---- tail: l1 activation, l2, l3; 32 threads per row ----
    const int r = t >> 5;   // row 0..7
    const int q = t & 31;   // 32 threads per row
    const int rowb = rows_s[r];

    if (q < 16) {
        const int o = q;
        float v = part_s[0][r][o] + part_s[1][r][o] + part_s[2][r][o]
                + part_s[3][r][o] + mb[e * NO1 + o];
        if (o < 15) {
            l1x_s[r][o]      = clamp01(v * v * (255.0f / 256.0f));
            l1x_s[r][o + 15] = clamp01(v);
        } else {
            l1c15_s[r] = v;
        }
    }
    __syncthreads();

    // each thread one l2 output (q = 0..31)
    float a2 = l2b[e * NL3 + q];
    const float* w2r = l2w + (size_t)e * NL3 * NL2D + q * NL2D;
#pragma unroll
    for (int i = 0; i < NL2D; ++i) a2 = fmaf(l1x_s[r][i], w2r[i], a2);
    a2 = clamp01(a2);
    float pacc = a2 * ow[e * NL3 + q];
    pacc += __shfl_xor(pacc, 1);
    pacc += __shfl_xor(pacc, 2);
    pacc += __shfl_xor(pacc, 4);
    pacc += __shfl_xor(pacc, 8);
    pacc += __shfl_xor(pacc, 16);

    if (q == 0 && rowb >= 0) {
        out[rowb] = pacc + ob[e] + l1c15_s[r];
    }
}

extern "C" void kernel_launch(void* const* d_in, const int* in_sizes, int n_in,
                              void* d_out, int out_size, void* d_ws, size_t ws_size,
                              hipStream_t stream)
{
    const float* x    = (const float*)d_in[0];
    const float* rin  = (const float*)d_in[1];
    const float* rw   = (const float*)d_in[2];
    const float* rb   = (const float*)d_in[3];
    const float* l1w  = (const float*)d_in[4];
    const float* l1b  = (const float*)d_in[5];
    const float* l1fw = (const float*)d_in[6];
    const float* l1fb = (const float*)d_in[7];
    const float* l2w  = (const float*)d_in[8];
    const float* l2b  = (const float*)d_in[9];
    const float* ow   = (const float*)d_in[10];
    const float* ob   = (const float*)d_in[11];
    float* out = (float*)d_out;

    char* ws = (char*)d_ws;
    int*   cursors = (int*)(ws + WS_CURSORS);
    int*   offpad  = (int*)(ws + WS_OFFPAD);
    int*   idx     = (int*)(ws + WS_IDX);
    int*   bucket  = (int*)(ws + WS_BUCKET);
    float* mb      = (float*)(ws + WS_MB);
    float* mw      = (float*)(ws + WS_MW);
    int*   blk_cnt  = (int*)(ws + WS_BLK_CNT);
    float* blk_sump = (float*)(ws + WS_BLK_SUMP);
    float* blk_z    = (float*)(ws + WS_BLK_Z);
    float* blk_ent  = (float*)(ws + WS_BLK_ENT);
    float* blk_top  = (float*)(ws + WS_BLK_TOP);

    hipMemsetAsync(ws, 0, 256, stream);
    hipMemsetAsync(ws + WS_BUCKET, 0xFF, (size_t)(NB + 256) * 4, stream);

    router2_kernel<<<NB / 64, 256, 0, stream>>>(rin, rw, rb, idx, blk_cnt, blk_sump,
                                                blk_z, blk_ent, blk_top);
    merge_kernel<<<(NE * NO1 * ND + 255) / 256, 256, 0, stream>>>(l1w, l1b, l1fw, l1fb, mw, mb);
    finalize2_kernel<<<1, 256, 0, stream>>>(blk_cnt, blk_sump, blk_z, blk_ent, blk_top,
                                            offpad, out);
    scatter_kernel<<<NB / 256, 256, 0, stream>>>(idx, offpad, cursors, bucket);
    moe_main_kernel<<<(NB + 256) / 8, 256, 0, stream>>>(x, mw, mb, l2w, l2b, ow, ob,
                                                        bucket, offpad, out);
}

// Round 7
// 98.159 us; speedup vs baseline: 1.8869x; 1.4169x over previous
//
#include <hip/hip_runtime.h>

constexpr int NB  = 16384;  // batch
constexpr int ND  = 3072;   // D
constexpr int NR  = 256;    // R
constexpr int NE  = 8;      // experts
constexpr int NO1 = 16;     // L2+1 outputs of l1
constexpr int NL2D = 30;    // 2*L2
constexpr int NL3 = 32;     // L3

// ---- workspace layout (bytes) ----
constexpr size_t WS_CURSORS = 32;     // int[8]
constexpr size_t WS_OFFPAD  = 128;    // int[9]
constexpr size_t WS_IDX     = 256;                    // int[NB]
constexpr size_t WS_BUCKET  = WS_IDX + (size_t)NB*4;  // int[NB+256]
constexpr size_t WS_MB      = WS_BUCKET + (size_t)(NB+256)*4; // float[128]
constexpr size_t WS_MW      = WS_MB + 512;            // float[128*3072]
constexpr size_t WS_BLK_CNT  = WS_MW + (size_t)128*3072*4;   // int[256*8]
constexpr size_t WS_BLK_SUMP = WS_BLK_CNT + 8192;            // float[256*8]
constexpr size_t WS_BLK_Z    = WS_BLK_SUMP + 8192;           // float[256]
constexpr size_t WS_BLK_ENT  = WS_BLK_Z + 1024;              // float[256]
constexpr size_t WS_BLK_TOP  = WS_BLK_ENT + 1024;            // float[256]

__device__ __forceinline__ float clamp01(float v) { return fminf(fmaxf(v, 0.0f), 1.0f); }

// async global->LDS DMA, 16B per lane; LDS dest = wave-uniform base + lane*16
__device__ __forceinline__ void stage16(const float* g, float* l) {
    __builtin_amdgcn_global_load_lds(
        (const __attribute__((address_space(1))) unsigned int*)g,
        (__attribute__((address_space(3))) unsigned int*)l,
        16, 0, 0);
}

// ---------------- Router v2: 64 rows/block, 4 threads/row ----------------
__global__ __launch_bounds__(256) void router2_kernel(
    const float* __restrict__ rin, const float* __restrict__ rw,
    const float* __restrict__ rb, int* __restrict__ idx,
    int* __restrict__ blk_cnt, float* __restrict__ blk_sump,
    float* __restrict__ blk_z, float* __restrict__ blk_ent, float* __restrict__ blk_top)
{
    __shared__ float w_s[NE][NR];          // 8 KB
    __shared__ float red_f[4][11];
    __shared__ int   red_c[4][8];

    const int t = threadIdx.x;
    {
        const float4* src = (const float4*)rw;
        float4* dst = (float4*)&w_s[0][0];
        dst[t]       = src[t];
        dst[t + 256] = src[t + 256];
    }
    __syncthreads();

    const int q  = t & 3;          // quarter of the row (64 elems each)
    const int rr = t >> 2;         // row within block, 0..63
    const int b  = blockIdx.x * 64 + rr;
    const float* rp = rin + (size_t)b * NR + q * 64;

    float acc[NE];
#pragma unroll
    for (int e = 0; e < NE; ++e) acc[e] = 0.0f;

#pragma unroll
    for (int c = 0; c < 16; ++c) {
        const float4 xv = *(const float4*)(rp + c * 4);
#pragma unroll
        for (int e = 0; e < NE; ++e) {
            const float4 wv = *(const float4*)(&w_s[e][q * 64 + c * 4]);
            acc[e] = fmaf(xv.x, wv.x, acc[e]);
            acc[e] = fmaf(xv.y, wv.y, acc[e]);
            acc[e] = fmaf(xv.z, wv.z, acc[e]);
            acc[e] = fmaf(xv.w, wv.w, acc[e]);
        }
    }
    float lg[NE];
#pragma unroll
    for (int e = 0; e < NE; ++e) {
        float v = acc[e];
        v += __shfl_xor(v, 1);
        v += __shfl_xor(v, 2);
        lg[e] = v + rb[e];
    }

    float m = lg[0]; int am = 0;
#pragma unroll
    for (int e = 1; e < NE; ++e) { if (lg[e] > m) { m = lg[e]; am = e; } }
    float p[NE]; float ssum = 0.0f;
#pragma unroll
    for (int e = 0; e < NE; ++e) { p[e] = __expf(lg[e] - m); ssum += p[e]; }
    const float inv = 1.0f / ssum;
    const float lse = m + __logf(ssum);

    const bool active = (q == 0);
    float sv[11];
    float ent = 0.0f, top = 0.0f;
#pragma unroll
    for (int e = 0; e < NE; ++e) {
        const float pj = p[e] * inv;
        sv[e] = pj;
        ent -= pj * __logf(fmaxf(pj, 1e-9f));
        top = fmaxf(top, pj);
    }
    sv[8] = lse * lse;
    sv[9] = ent;
    sv[10] = top;
    if (!active) {
#pragma unroll
        for (int i = 0; i < 11; ++i) sv[i] = 0.0f;
    }
    if (active) idx[b] = am;

#pragma unroll
    for (int i = 0; i < 11; ++i) {
        float v = sv[i];
        v += __shfl_xor(v, 4);
        v += __shfl_xor(v, 8);
        v += __shfl_xor(v, 16);
        v += __shfl_xor(v, 32);
        sv[i] = v;
    }
    int cnt[NE];
#pragma unroll
    for (int j = 0; j < NE; ++j) {
        unsigned long long mk = __ballot(active && (am == j));
        cnt[j] = __popcll(mk);
    }

    const int wave = t >> 6;
    if ((t & 63) == 0) {
#pragma unroll
        for (int i = 0; i < 11; ++i) red_f[wave][i] = sv[i];
#pragma unroll
        for (int j = 0; j < NE; ++j) red_c[wave][j] = cnt[j];
    }
    __syncthreads();

    const int bid = blockIdx.x;
    if (t < 8) {
        blk_sump[bid * 8 + t] = red_f[0][t] + red_f[1][t] + red_f[2][t] + red_f[3][t];
        blk_cnt [bid * 8 + t] = red_c[0][t] + red_c[1][t] + red_c[2][t] + red_c[3][t];
    } else if (t == 8) {
        blk_z[bid]   = red_f[0][8] + red_f[1][8] + red_f[2][8] + red_f[3][8];
    } else if (t == 9) {
        blk_ent[bid] = red_f[0][9] + red_f[1][9] + red_f[2][9] + red_f[3][9];
    } else if (t == 10) {
        blk_top[bid] = red_f[0][10] + red_f[1][10] + red_f[2][10] + red_f[3][10];
    }
}

// ---------------- Merge l1 weights: merged = l1_w + tile(l1f_w) ----------------
__global__ __launch_bounds__(256) void merge_kernel(
    const float* __restrict__ l1w, const float* __restrict__ l1b,
    const float* __restrict__ l1fw, const float* __restrict__ l1fb,
    float* __restrict__ mw, float* __restrict__ mb)
{
    const int i = blockIdx.x * 256 + threadIdx.x;
    const int total = NE * NO1 * ND;   // 128*3072
    if (i < total) {
        mw[i] = l1w[i] + l1fw[i % (NO1 * ND)];
    }
    if (i < NE * NO1) {
        mb[i] = l1b[i] + l1fb[i & (NO1 - 1)];
    }
}

// ---------------- Finalize v2: reduce 256 per-block partials ----------------
__global__ __launch_bounds__(256) void finalize2_kernel(
    const int* __restrict__ blk_cnt, const float* __restrict__ blk_sump,
    const float* __restrict__ blk_z, const float* __restrict__ blk_ent,
    const float* __restrict__ blk_top, int* __restrict__ offpad,
    float* __restrict__ out)
{
    __shared__ float ps_s[32][8];
    __shared__ int   pc_s[32][8];
    __shared__ float zet_s[3][4];
    __shared__ float tot_f[8];
    __shared__ int   tot_c[8];

    const int t = threadIdx.x;
    {
        const int e = t & 7, g = t >> 3;
        float ps = 0.0f; int pc = 0;
#pragma unroll
        for (int k = 0; k < 8; ++k) {
            const int bb = g * 8 + k;
            ps += blk_sump[bb * 8 + e];
            pc += blk_cnt [bb * 8 + e];
        }
        ps_s[g][e] = ps;
        pc_s[g][e] = pc;
    }
    {
        float z = blk_z[t], en = blk_ent[t], tp = blk_top[t];
#pragma unroll
        for (int o = 1; o < 64; o <<= 1) {
            z  += __shfl_xor(z, o);
            en += __shfl_xor(en, o);
            tp += __shfl_xor(tp, o);
        }
        const int wave = t >> 6;
        if ((t & 63) == 0) { zet_s[0][wave] = z; zet_s[1][wave] = en; zet_s[2][wave] = tp; }
    }
    __syncthreads();

    if (t < 8) {
        float s = 0.0f; int c = 0;
        for (int g = 0; g < 32; ++g) { s += ps_s[g][t]; c += pc_s[g][t]; }
        tot_f[t] = s; tot_c[t] = c;
    }
    __syncthreads();

    if (t == 0) {
        int run = 0;
#pragma unroll
        for (int e = 0; e < NE; ++e) {
            offpad[e] = run;
            run += (tot_c[e] + 31) & ~31;
        }
        offpad[NE] = run;

        const float invB = 1.0f / (float)NB;
        float aux = 0.0f;
        float frac[NE], avg[NE];
#pragma unroll
        for (int e = 0; e < NE; ++e) {
            frac[e] = (float)tot_c[e] * invB;
            avg[e]  = tot_f[e] * invB;
            aux += frac[e] * avg[e];
        }
        aux *= (float)NE;
        const float z   = (zet_s[0][0] + zet_s[0][1] + zet_s[0][2] + zet_s[0][3]) * invB;
        const float ent = (zet_s[1][0] + zet_s[1][1] + zet_s[1][2] + zet_s[1][3]) * invB;
        const float top = (zet_s[2][0] + zet_s[2][1] + zet_s[2][2] + zet_s[2][3]) * invB;
        const float rl  = 0.01f * aux + 0.001f * z;

        float* o = out + NB;
        o[0] = rl;
        o[1] = aux;
        o[2] = z;
#pragma unroll
        for (int e = 0; e < NE; ++e) o[3 + e]  = frac[e];
#pragma unroll
        for (int e = 0; e < NE; ++e) o[11 + e] = avg[e];
        o[19] = ent / __logf(8.0f);
        o[20] = top;
    }
}

// ---------------- Scatter rows into expert buckets (wave-aggregated atomics) ----------------
__global__ __launch_bounds__(256) void scatter_kernel(
    const int* __restrict__ idx, const int* __restrict__ offpad,
    int* __restrict__ cursors, int* __restrict__ bucket)
{
    const int b = blockIdx.x * 256 + threadIdx.x;
    const int e = idx[b];
    const int lane = threadIdx.x & 63;
#pragma unroll
    for (int ee = 0; ee < NE; ++ee) {
        unsigned long long mask = __ballot(e == ee);
        if (e == ee) {
            int leader = __ffsll((unsigned long long)mask) - 1;
            int cnt = __popcll(mask);
            int base = 0;
            if (lane == leader) base = atomicAdd(&cursors[ee], cnt);
            base = __shfl(base, leader);
            int pos = base + __popcll(mask & ((1ull << lane) - 1ull));
            bucket[offpad[ee] + pos] = b;
        }
    }
}

// ---------------- Main v7: async LDS-staged x, per-wave o-quad over full K ----
// 8 rows/block, 4 waves. Per 128-k chunk: each wave DMA-stages 2 rows (linear
// dest, per-lane global src) into x_lds[buf], double-buffered; compute reads x
// from LDS (lgkmcnt domain) + 4 weight float4 from L2, 64 FMAs into acc[4][4].
// Wave wid owns outputs 4*wid..4*wid+3 for ALL rows and ALL K (no K-split).
// VGPR ~60 -> high occupancy; staging for chunk c+1 hides under compute of c.
__global__ __launch_bounds__(256) void moe_main_kernel(
    const float* __restrict__ x, const float* __restrict__ mw,
    const float* __restrict__ mb, const float* __restrict__ l2w,
    const float* __restrict__ l2b, const float* __restrict__ ow,
    const float* __restrict__ ob, const int* __restrict__ bucket,
    const int* __restrict__ offpad, float* __restrict__ out)
{
    __shared__ float x_lds[2][8][128];    // 8 KB, double-buffered x chunks
    __shared__ int   rows_s[8];
    __shared__ int   expert_s;
    __shared__ float l1c_s[8][16];
    __shared__ float l1x_s[8][30];
    __shared__ float l1c15_s[8];

    const int t = threadIdx.x;
    const int slot0 = blockIdx.x * 8;
    if (t < 8) rows_s[t] = bucket[slot0 + t];
    if (t == 0) {
        int e = 0;
#pragma unroll
        for (int j = 1; j < NE; ++j) if (slot0 >= offpad[j]) e = j;
        expert_s = e;
    }
    __syncthreads();

    const int e    = expert_s;
    const int wid  = t >> 6;       // wave 0..3 -> owns o-quad 4*wid..4*wid+3
    const int lane = t & 63;
    const int half = lane >> 5;    // wave's staged row pair: 2*wid + half
    const int s    = lane & 31;    // k-slice within chunk (float4 granules)
    const int rgrp = half;         // compute rows rgrp*4 .. rgrp*4+3

    // staging source: lane covers 16B of row (2*wid+half) at chunk base
    int srow = rows_s[2 * wid + half];
    if (srow < 0) srow = 0;
    const float* stage_src = x + (size_t)srow * ND + s * 4;
    float* stage_dst0 = &x_lds[0][2 * wid][0];   // lanes spread linearly by 16B
    float* stage_dst1 = &x_lds[1][2 * wid][0];

    const float* wbase = mw + (size_t)e * NO1 * ND + (size_t)(4 * wid) * ND;

    float acc[4][4];
#pragma unroll
    for (int rr = 0; rr < 4; ++rr)
#pragma unroll
        for (int oo = 0; oo < 4; ++oo) acc[rr][oo] = 0.0f;

    // prologue: stage chunk 0 into buf 0
    stage16(stage_src, stage_dst0);
    __syncthreads();

    for (int c = 0; c < 24; ++c) {
        const int cur = c & 1;
        if (c + 1 < 24)
            stage16(stage_src + (c + 1) * 128, cur ? stage_dst0 : stage_dst1);

        const float* wk = wbase + c * 128 + s * 4;
        const float4 wv0 = *(const float4*)(wk);
        const float4 wv1 = *(const float4*)(wk + ND);
        const float4 wv2 = *(const float4*)(wk + 2 * ND);
        const float4 wv3 = *(const float4*)(wk + 3 * ND);

        float4 xv[4];
#pragma unroll
        for (int rr = 0; rr < 4; ++rr)
            xv[rr] = *(const float4*)&x_lds[cur][rgrp * 4 + rr][s * 4];

#pragma unroll
        for (int rr = 0; rr < 4; ++rr) {
            acc[rr][0] = fmaf(xv[rr].x, wv0.x, acc[rr][0]);
            acc[rr][0] = fmaf(xv[rr].y, wv0.y, acc[rr][0]);
            acc[rr][0] = fmaf(xv[rr].z, wv0.z, acc[rr][0]);
            acc[rr][0] = fmaf(xv[rr].w, wv0.w, acc[rr][0]);
            acc[rr][1] = fmaf(xv[rr].x, wv1.x, acc[rr][1]);
            acc[rr][1] = fmaf(xv[rr].y, wv1.y, acc[rr][1]);
            acc[rr][1] = fmaf(xv[rr].z, wv1.z, acc[rr][1]);
            acc[rr][1] = fmaf(xv[rr].w, wv1.w, acc[rr][1]);
            acc[rr][2] = fmaf(xv[rr].x, wv2.x, acc[rr][2]);
            acc[rr][2] = fmaf(xv[rr].y, wv2.y, acc[rr][2]);
            acc[rr][2] = fmaf(xv[rr].z, wv2.z, acc[rr][2]);
            acc[rr][2] = fmaf(xv[rr].w, wv2.w, acc[rr][2]);
            acc[rr][3] = fmaf(xv[rr].x, wv3.x, acc[rr][3]);
            acc[rr][3] = fmaf(xv[rr].y, wv3.y, acc[rr][3]);
            acc[rr][3] = fmaf(xv[rr].z, wv3.z, acc[rr][3]);
            acc[rr][3] = fmaf(xv[rr].w, wv3.w, acc[rr][3]);
        }
        __syncthreads();   // drains next-chunk DMA; guards buffer reuse
    }

    // reduce over the 32 s-lanes (stays within 32-lane halves)
#pragma unroll
    for (int rr = 0; rr < 4; ++rr)
#pragma unroll
        for (int oo = 0; oo < 4; ++oo) {
            float a = acc[rr][oo];
            a += __shfl_xor(a, 1);
            a += __shfl_xor(a, 2);
            a += __shfl_xor(a, 4);
            a += __shfl_xor(a, 8);
            a += __shfl_xor(a, 16);
            acc[rr][oo] = a;
        }
    if (s == 0) {
#pragma unroll
        for (int rr = 0; rr < 4; ++rr)
#pragma unroll
            for (int oo = 0; oo < 4; ++oo)
                l1c_s[rgrp * 4 + rr][4 * wid + oo] = acc[rr][oo];
    }
    __syncthreads();

    // ---- tail: l1 activation, l2, l3; 32 threads per row ----
    const int r = t >> 5;   // row 0..7
    const int q = t & 31;   // 32 threads per row
    const int rowb = rows_s[r];

    if (q < 16) {
        const int o = q;
        float v = l1c_s[r][o] + mb[e * NO1 + o];
        if (o < 15) {
            l1x_s[r][o]      = clamp01(v * v * (255.0f / 256.0f));
            l1x_s[r][o + 15] = clamp01(v);
        } else {
            l1c15_s[r] = v;
        }
    }
    __syncthreads();

    // each thread one l2 output (q = 0..31)
    float a2 = l2b[e * NL3 + q];
    const float* w2r = l2w + (size_t)e * NL3 * NL2D + q * NL2D;
#pragma unroll
    for (int i = 0; i < NL2D; ++i) a2 = fmaf(l1x_s[r][i], w2r[i], a2);
    a2 = clamp01(a2);
    float pacc = a2 * ow[e * NL3 + q];
    pacc += __shfl_xor(pacc, 1);
    pacc += __shfl_xor(pacc, 2);
    pacc += __shfl_xor(pacc, 4);
    pacc += __shfl_xor(pacc, 8);
    pacc += __shfl_xor(pacc, 16);

    if (q == 0 && rowb >= 0) {
        out[rowb] = pacc + ob[e] + l1c15_s[r];
    }
}

extern "C" void kernel_launch(void* const* d_in, const int* in_sizes, int n_in,
                              void* d_out, int out_size, void* d_ws, size_t ws_size,
                              hipStream_t stream)
{
    const float* x    = (const float*)d_in[0];
    const float* rin  = (const float*)d_in[1];
    const float* rw   = (const float*)d_in[2];
    const float* rb   = (const float*)d_in[3];
    const float* l1w  = (const float*)d_in[4];
    const float* l1b  = (const float*)d_in[5];
    const float* l1fw = (const float*)d_in[6];
    const float* l1fb = (const float*)d_in[7];
    const float* l2w  = (const float*)d_in[8];
    const float* l2b  = (const float*)d_in[9];
    const float* ow   = (const float*)d_in[10];
    const float* ob   = (const float*)d_in[11];
    float* out = (float*)d_out;

    char* ws = (char*)d_ws;
    int*   cursors = (int*)(ws + WS_CURSORS);
    int*   offpad  = (int*)(ws + WS_OFFPAD);
    int*   idx     = (int*)(ws + WS_IDX);
    int*   bucket  = (int*)(ws + WS_BUCKET);
    float* mb      = (float*)(ws + WS_MB);
    float* mw      = (float*)(ws + WS_MW);
    int*   blk_cnt  = (int*)(ws + WS_BLK_CNT);
    float* blk_sump = (float*)(ws + WS_BLK_SUMP);
    float* blk_z    = (float*)(ws + WS_BLK_Z);
    float* blk_ent  = (float*)(ws + WS_BLK_ENT);
    float* blk_top  = (float*)(ws + WS_BLK_TOP);

    hipMemsetAsync(ws, 0, 256, stream);
    hipMemsetAsync(ws + WS_BUCKET, 0xFF, (size_t)(NB + 256) * 4, stream);

    router2_kernel<<<NB / 64, 256, 0, stream>>>(rin, rw, rb, idx, blk_cnt, blk_sump,
                                                blk_z, blk_ent, blk_top);
    merge_kernel<<<(NE * NO1 * ND + 255) / 256, 256, 0, stream>>>(l1w, l1b, l1fw, l1fb, mw, mb);
    finalize2_kernel<<<1, 256, 0, stream>>>(blk_cnt, blk_sump, blk_z, blk_ent, blk_top,
                                            offpad, out);
    scatter_kernel<<<NB / 256, 256, 0, stream>>>(idx, offpad, cursors, bucket);
    moe_main_kernel<<<(NB + 256) / 8, 256, 0, stream>>>(x, mw, mb, l2w, l2b, ow, ob,
                                                        bucket, offpad, out);
}